// Round 4
// baseline (1792.549 us; speedup 1.0000x reference)
//
#include <hip/hip_runtime.h>

// ---------------------------------------------------------------------------
// VMLMF group-GRU, B=256 T=512 N=h=256 L=2, ranks cat to 96.
// Inputs fp32 (auto-sniffed hedge), OUTPUT fp32 (reference dtype).
// Precision: fp16 MFMA operands, fp32 accumulate, hi/lo M-slot packing.
// Per layer, T-chunked to fit any ws_size:
//   g12:  wxc[B*steps,768] = (x[:,t0:..] @ [Wd|Wo]) @ [Wdg;Wog] + b  (fp32 out)
//   scan: `steps` sequential GRU steps, 1 WG per batch row, U/G MFMA
//         B-fragments pinned in VGPRs; h fp32 carry across chunks.
// R4: full revert to the verified 2177us baseline scan structure
//   (3x __syncthreads, cross-wave uh exchange, gf tiles w*12+nt). R1-R3's
//   wave-private-uh remap (b) is abandoned: it failed deterministically
//   (absmax 1.6758 identical across builds) despite repeatedly-verified
//   index math — root cause not identifiable by inspection; needs on-device
//   probing that this harness can't do incrementally.
//   ONE value-identical code motion kept: xout store of h(t-1) and the wx
//   loads for step t are issued at the TOP of iteration t (epilogue stores
//   the last h). Same barrier intervals, same arithmetic; the vmcnt(0)
//   drain at the next __syncthreads now happens a GEMM-A later than issue,
//   hiding store-ack / wxc-read latency behind MFMA work.
// ws: wbuf f16 weights+bias | hstate[256*256] f32 | wxc f32 chunk.
// ---------------------------------------------------------------------------

typedef _Float16 f16x8 __attribute__((ext_vector_type(8)));
typedef float    f32x4 __attribute__((ext_vector_type(4)));

#define MFMA16(a, b, c) __builtin_amdgcn_mfma_f32_16x16x32_f16((a), (b), (c), 0, 0, 0)

__device__ __forceinline__ float bf2f(unsigned short u) {
  unsigned int x = ((unsigned int)u) << 16;
  float f; __builtin_memcpy(&f, &x, 4); return f;
}
__device__ __forceinline__ unsigned short f2hu(float f) {   // f32 -> f16 bits (RNE)
  _Float16 h = (_Float16)f;
  unsigned short u; __builtin_memcpy(&u, &h, 2); return u;
}
__device__ __forceinline__ f16x8 ld8(const _Float16* p) {
  return *(const f16x8*)p;
}

// True iff buffer holds fp32 (low half-words look like huge-exponent bf16s).
__device__ __forceinline__ bool sniff_f32(const unsigned short* p) {
  int cnt = 0;
#pragma unroll 4
  for (int i = 0; i < 128; i += 2) {
    if ((p[i] & 0x7F80) >= 0x4800) cnt++;   // |bf16| >= 2^17: impossible for data
  }
  return cnt >= 4;
}
// weight fetch: fp32 or bf16 source -> f16 bits
__device__ __forceinline__ unsigned short geth(const void* p, size_t i, bool f32) {
  float v = f32 ? ((const float*)p)[i] : bf2f(((const unsigned short*)p)[i]);
  return f2hu(v);
}

// ---------------------------------------------------------------------------
// prep: transposed/concatenated f16 weights + bias.
// Per-layer block (el): Wt[96][256]@0, Ut[96][256]@24576, Wgt[768][96]@49152,
// Gt[768][96]@122880. Block 196608. Bias [2][768] @393216.
// ---------------------------------------------------------------------------
__global__ void prep_kernel(const unsigned short* __restrict__ xprobe,
                            const void* __restrict__ Wd,
                            const void* __restrict__ Wdg,
                            const void* __restrict__ Wo,
                            const void* __restrict__ Wog,
                            const void* __restrict__ Ud,
                            const void* __restrict__ Udg,
                            const void* __restrict__ Uo,
                            const void* __restrict__ Uog,
                            const void* __restrict__ bvec,
                            unsigned short* __restrict__ wbuf) {
  int idx = blockIdx.x * 256 + threadIdx.x;
  if (idx >= 394752) return;
  bool f32 = sniff_f32(xprobe);
  if (idx >= 393216) { wbuf[idx] = geth(bvec, idx - 393216, f32); return; }
  int l = idx / 196608, id = idx % 196608;
  unsigned short v;
  if (id < 24576) {                         // Wt[n][k]
    int n = id >> 8, k = id & 255;
    v = (n < 64) ? geth(Wd, (size_t)l * 16384 + k * 64 + n, f32)
                 : geth(Wo, (size_t)l * 8192 + k * 32 + (n - 64), f32);
  } else if (id < 49152) {                  // Ut[n][k]
    int q = id - 24576; int n = q >> 8, k = q & 255;
    v = (n < 64) ? geth(Ud, (size_t)l * 16384 + k * 64 + n, f32)
                 : geth(Uo, (size_t)l * 8192 + k * 32 + (n - 64), f32);
  } else if (id < 122880) {                 // Wgt[n][k]
    int q = id - 49152; int n = q / 96, k = q % 96;
    v = (k < 64) ? geth(Wdg, (size_t)l * 49152 + k * 768 + n, f32)
                 : geth(Wog, (size_t)l * 24576 + (k - 64) * 768 + n, f32);
  } else {                                  // Gt[n][k]
    int q = id - 122880; int n = q / 96, k = q % 96;
    v = (k < 64) ? geth(Udg, (size_t)l * 49152 + k * 768 + n, f32)
                 : geth(Uog, (size_t)l * 24576 + (k - 64) * 768 + n, f32);
  }
  wbuf[(size_t)l * 196608 + id] = v;
}

// ---------------------------------------------------------------------------
// g12: wxc = (X-chunk @ W) @ Wg + b (fp32 result). 64 chunk-rows/WG.
// xmode: 0 = X bf16, 1 = sniff, 2 = X fp32.
// Chunk row R = b*steps + i  ->  X row b*512 + t0 + i.
// ---------------------------------------------------------------------------
__global__ __launch_bounds__(256) void g12_kernel(
    const void* __restrict__ X,              // [131072,256] bf16 or f32
    int xmode,
    const _Float16* __restrict__ Wt,         // [96,256] f16
    const _Float16* __restrict__ Wgt,        // [768,96] f16
    const _Float16* __restrict__ bv,         // [768] f16
    float* __restrict__ wxc,                 // [256*steps,768] fp32
    int t0, int lsteps) {
  __shared__ __align__(16) _Float16 Pl[64 * 104];
  const int tid = threadIdx.x;
  const int w = tid >> 6, lane = tid & 63;
  const int ml = lane & 15, kg = lane >> 4;
  const int r0 = blockIdx.x * 64;
  const int smask = (1 << lsteps) - 1;
  const f32x4 z4 = {0.f, 0.f, 0.f, 0.f};

  const bool xf32 = (xmode == 2) ||
                    (xmode == 1 && sniff_f32((const unsigned short*)X));

  // GEMM1: P[16,96] = Xrows @ W[256,96]
  f32x4 acc1[6];
  const int R = r0 + w * 16 + ml;
  const int xrow = ((R >> lsteps) << 9) + t0 + (R & smask);
  const size_t abase = (size_t)xrow * 256 + kg * 8;
#pragma unroll
  for (int ks = 0; ks < 8; ks++) {
    f16x8 a;
    if (xf32) {
      const float* p = (const float*)X + abase + ks * 32;
#pragma unroll
      for (int j = 0; j < 8; j++) a[j] = (_Float16)p[j];
    } else {
      const unsigned short* p = (const unsigned short*)X + abase + ks * 32;
#pragma unroll
      for (int j = 0; j < 8; j++) a[j] = (_Float16)bf2f(p[j]);
    }
#pragma unroll
    for (int nt = 0; nt < 6; nt++) {
      f16x8 b = ld8(Wt + (nt * 16 + ml) * 256 + ks * 32 + kg * 8);
      acc1[nt] = MFMA16(a, b, ks ? acc1[nt] : z4);
    }
  }
#pragma unroll
  for (int nt = 0; nt < 6; nt++)
#pragma unroll
    for (int r = 0; r < 4; r++)
      Pl[(w * 16 + kg * 4 + r) * 104 + nt * 16 + ml] = (_Float16)acc1[nt][r];
  __syncthreads();

  // GEMM2: wxc[16,768] = P[16,96] @ Wg[96,768] + b
  f16x8 afr[3];
#pragma unroll
  for (int ks = 0; ks < 3; ks++)
    afr[ks] = ld8(Pl + (w * 16 + ml) * 104 + ks * 32 + kg * 8);
#pragma unroll
  for (int half = 0; half < 2; half++) {
    f32x4 acc[24];
#pragma unroll
    for (int ks = 0; ks < 3; ks++)
#pragma unroll
      for (int nt = 0; nt < 24; nt++) {
        int cb = half * 384 + nt * 16;
        f16x8 b = ld8(Wgt + (size_t)(cb + ml) * 96 + ks * 32 + kg * 8);
        acc[nt] = MFMA16(afr[ks], b, ks ? acc[nt] : z4);
      }
#pragma unroll
    for (int nt = 0; nt < 24; nt++) {
      int cb = half * 384 + nt * 16;
      float bias = (float)bv[cb + ml];
#pragma unroll
      for (int r = 0; r < 4; r++)
        wxc[(size_t)(r0 + w * 16 + kg * 4 + r) * 768 + cb + ml] =
            acc[nt][r] + bias;
    }
  }
}

// ---------------------------------------------------------------------------
// scan: one WG per batch row; `steps` GRU steps; h carried fp32 in hstate.
// M-slot packing: A-row0 = hi, A-row1 = lo residual; result = Drow0 + Drow1
// (exact h / t1 into the fp16 GEMMs; only static weight quant remains).
// GEMM A: t1[96]  = h[256] @ U[256,96]   (A from LDS, U pinned in VGPRs)
// GEMM B: uh[768] = t1[96] @ G[96,768]   (G pinned in VGPRs)
// Baseline sync structure: 3x __syncthreads per step. xout store / wx loads
// issue at loop-top so their vmcnt drain lands a GEMM-A later (hidden).
// ---------------------------------------------------------------------------
__global__ __launch_bounds__(256, 1) void scan_kernel(
    const float* __restrict__ wxc,           // [256*steps,768] fp32
    const _Float16* __restrict__ Ut,         // [96,256] f16
    const _Float16* __restrict__ Gt,         // [768,96] f16
    float* __restrict__ xout,                // [B*T,256] fp32 full tensor
    float* __restrict__ hstate,              // [256,256] fp32 carry
    float* __restrict__ hT,                  // pre-offset; stride 512 per b
    int t0, int steps, int first) {
  __shared__ __align__(16) _Float16 hp_lds[512];   // [0:256)=hi, [256:512)=lo
  __shared__ __align__(16) _Float16 t1_lds[192];   // [0:96)=hi, [96:192)=lo
  __shared__ float uh_lds[768];
  const int tid = threadIdx.x;
  const int b = blockIdx.x;
  const int w = tid >> 6, lane = tid & 63;
  const int ml = lane & 15, kg = lane >> 4;
  const f32x4 z4 = {0.f, 0.f, 0.f, 0.f};

  // GEMM-A N-tile assignment: w0:{0,1} w1:{2,3} w2:{4} w3:{5}
  const int tA = (w < 2) ? 2 * w : (2 + w);
  f16x8 uf[2][8];
#pragma unroll
  for (int i = 0; i < 2; i++) {
    int tile = tA + i; if (tile > 5) tile = 5;
    const _Float16* up = Ut + (size_t)(tile * 16 + ml) * 256 + kg * 8;
#pragma unroll
    for (int ks = 0; ks < 8; ks++) uf[i][ks] = ld8(up + ks * 32);
  }
  // GEMM-B fragments: wave w owns cols [w*192, w*192+192)
  f16x8 gf[12][3];
#pragma unroll
  for (int nt = 0; nt < 12; nt++) {
    const _Float16* gp = Gt + (size_t)((w * 12 + nt) * 16 + ml) * 96 + kg * 8;
#pragma unroll
    for (int ks = 0; ks < 3; ks++) gf[nt][ks] = ld8(gp + ks * 32);
  }

  float hcur = first ? 0.f : hstate[b * 256 + tid];
  {
    _Float16 hi = (_Float16)hcur;
    hp_lds[tid] = hi;
    hp_lds[256 + tid] = (_Float16)(hcur - (float)hi);
  }
  const float* wrow = wxc + (size_t)b * steps * 768;
  __syncthreads();

  // A-row0 (lanes ml even) reads hi, A-row1 (ml odd) reads lo; rows 2-15
  // are don't-care (they read hi/lo again — valid numbers, rows ignored).
  const _Float16* hpf = hp_lds + (ml & 1) * 256 + kg * 8;
  const _Float16* t1f = t1_lds + (ml & 1) * 96 + kg * 8;

  for (int t = 0; t < steps; t++) {
    // Issue previous step's output store + this step's wx loads here: the
    // next vmcnt drain (__syncthreads #1) is a full GEMM-A away, so the
    // store-ack / wxc-read latency hides behind MFMA+LDS work.
    if (t > 0) xout[(size_t)(b * 512 + t0 + t - 1) * 256 + tid] = hcur;
    const float* cw = wrow + (size_t)t * 768;
    float wz = cw[tid], wr = cw[256 + tid], wc = cw[512 + tid];

    // ---- GEMM A (two independent K-half chains per tile) ----
    f32x4 aA0[2], aA1[2];
#pragma unroll
    for (int ks = 0; ks < 8; ks++) {
      f16x8 a = ld8(hpf + ks * 32);
      int hh = ks >> 2;
      aA0[hh] = MFMA16(a, uf[0][ks], (ks & 3) ? aA0[hh] : z4);
      if (w < 2) aA1[hh] = MFMA16(a, uf[1][ks], (ks & 3) ? aA1[hh] : z4);
    }
    if (lane < 16) {               // reg0 = hi-row result, reg1 = lo-row result
      float v0 = aA0[0][0] + aA0[0][1] + aA0[1][0] + aA0[1][1];
      _Float16 hi0 = (_Float16)v0;
      t1_lds[tA * 16 + lane] = hi0;
      t1_lds[96 + tA * 16 + lane] = (_Float16)(v0 - (float)hi0);
      if (w < 2) {
        float v1 = aA1[0][0] + aA1[0][1] + aA1[1][0] + aA1[1][1];
        _Float16 hi1 = (_Float16)v1;
        t1_lds[(tA + 1) * 16 + lane] = hi1;
        t1_lds[96 + (tA + 1) * 16 + lane] = (_Float16)(v1 - (float)hi1);
      }
    }
    __syncthreads();

    // ---- GEMM B ----
    f16x8 tf0 = ld8(t1f), tf1 = ld8(t1f + 32), tf2 = ld8(t1f + 64);
    f32x4 ub[12];
#pragma unroll
    for (int nt = 0; nt < 12; nt++) ub[nt] = MFMA16(tf0, gf[nt][0], z4);
#pragma unroll
    for (int nt = 0; nt < 12; nt++) ub[nt] = MFMA16(tf1, gf[nt][1], ub[nt]);
#pragma unroll
    for (int nt = 0; nt < 12; nt++) ub[nt] = MFMA16(tf2, gf[nt][2], ub[nt]);
    if (lane < 16) {
#pragma unroll
      for (int nt = 0; nt < 12; nt++)
        uh_lds[w * 192 + nt * 16 + lane] = ub[nt][0] + ub[nt][1];
    }
    __syncthreads();

    // ---- gates (thread tid owns hidden column tid) ----
    float uz = uh_lds[tid], ur = uh_lds[256 + tid], uc = uh_lds[512 + tid];
    float z = __builtin_amdgcn_rcpf(1.f + __expf(-(wz + uz)));
    float r = __builtin_amdgcn_rcpf(1.f + __expf(-(wr + ur)));
    float cc = 1.f - 2.f * __builtin_amdgcn_rcpf(1.f + __expf(2.f * (wc + r * uc)));
    hcur = z * hcur + (1.f - z) * cc;
    {
      _Float16 hi = (_Float16)hcur;
      hp_lds[tid] = hi;
      hp_lds[256 + tid] = (_Float16)(hcur - (float)hi);
    }
    __syncthreads();
  }
  xout[(size_t)(b * 512 + t0 + steps - 1) * 256 + tid] = hcur;
  hstate[b * 256 + tid] = hcur;
  hT[(size_t)b * 512 + tid] = hcur;
}

// ---------------------------------------------------------------------------
extern "C" void kernel_launch(void* const* d_in, const int* in_sizes, int n_in,
                              void* d_out, int out_size, void* d_ws, size_t ws_size,
                              hipStream_t stream) {
  (void)in_sizes; (void)n_in; (void)out_size;
  const unsigned short* x = (const unsigned short*)d_in[0];
  float* outF = (float*)d_out;

  // ws layout: wbuf f16 (394752 el = 789504 B) | hstate (256KB) | wxc f32
  unsigned short* wbuf   = (unsigned short*)d_ws;
  float*          hstate = (float*)((char*)d_ws + 790528);
  float*          wxc    = (float*)((char*)d_ws + 1052672);
  const size_t base = 1052672;
  const size_t wx_full = 402653184ull;        // 131072*768*4 bytes

  int nc = 1;
  while (nc < 256 && base + wx_full / nc > ws_size) nc <<= 1;
  const int steps = 512 / nc;
  int lsteps = 0; while ((1 << lsteps) < steps) lsteps++;

  float* xfin = outF;                          // [B,T,256] fp32; doubles as x2
  float* hTb  = outF + (size_t)131072 * 256;   // [B, 2, 256] fp32
  const _Float16* wbh = (const _Float16*)wbuf;
  const _Float16* bbf = wbh + 393216;

  hipLaunchKernelGGL(prep_kernel, dim3(1542), dim3(256), 0, stream,
                     x, d_in[1], d_in[2], d_in[3], d_in[4],
                     d_in[5], d_in[6], d_in[7], d_in[8], d_in[9], wbuf);

  const int g12_grid = (256 * steps) / 64;
  for (int l = 0; l < 2; l++) {
    const _Float16* wl = wbh + (size_t)l * 196608;
    const void* Xl = (l == 0) ? (const void*)x : (const void*)outF;
    const int xmode = (l == 0) ? 1 : 2;
    for (int c = 0; c < nc; c++) {
      hipLaunchKernelGGL(g12_kernel, dim3(g12_grid), dim3(256), 0, stream,
                         Xl, xmode, wl, wl + 49152, bbf + l * 768, wxc,
                         c * steps, lsteps);
      hipLaunchKernelGGL(scan_kernel, dim3(256), dim3(256), 0, stream,
                         wxc, wl + 24576, wl + 122880, xfin, hstate,
                         hTb + l * 256, c * steps, steps, (c == 0) ? 1 : 0);
    }
  }
}

// Round 5
// 1782.691 us; speedup vs baseline: 1.0055x; 1.0055x over previous
//
#include <hip/hip_runtime.h>

// ---------------------------------------------------------------------------
// VMLMF group-GRU, B=256 T=512 N=h=256 L=2, ranks cat to 96.
// Inputs fp32 (auto-sniffed hedge), OUTPUT fp32 (reference dtype).
// Precision: fp16 MFMA operands, fp32 accumulate, hi/lo M-slot packing.
//   g12:  wxc[B*steps,768] = (x[:,t0:..] @ [Wd|Wo]) @ [Wdg;Wog] + b  (fp32 out)
//   scan: `steps` sequential GRU steps, 1 WG per batch row, U/G MFMA
//         B-fragments pinned in VGPRs; h fp32 carry across chunks.
// R4 (passed, 1792us): loop-top xout store + wx loads (vmcnt drain hidden).
// R5: root cause of R1-R3 found — wave-private uh write->read is CROSS-LANE
//   within a wave; per-thread SIMT alias analysis lets LLVM hoist the uh
//   ds_read above the predicated ds_write (lanes>=16 provably don't alias).
//   Fix: explicit fence (asm memory clobber + lgkmcnt(0) + sched_barrier)
//   between uh write and gate reads. With that fixed, reinstate:
//   * wave-private uh (wave w owns cols s*256+w*64..+63) -> 2 barriers/step
//   * lgkmcnt-only double-fenced barriers (no vmcnt(0) drain at barriers)
// ws: wbuf f16 weights+bias | hstate[256*256] f32 | wxc f32 chunk.
// ---------------------------------------------------------------------------

typedef _Float16 f16x8 __attribute__((ext_vector_type(8)));
typedef float    f32x4 __attribute__((ext_vector_type(4)));

#define MFMA16(a, b, c) __builtin_amdgcn_mfma_f32_16x16x32_f16((a), (b), (c), 0, 0, 0)

// Barrier that does NOT drain vmcnt: LDS-visibility only (lgkmcnt), keeps
// global prefetch loads / fire-and-forget stores in flight across the sync.
// Double-fenced: no LDS op can move across s_barrier in either direction.
#define BAR_LDS()                                            \
  do {                                                       \
    asm volatile("s_waitcnt lgkmcnt(0)" ::: "memory");       \
    __builtin_amdgcn_s_barrier();                            \
    asm volatile("" ::: "memory");                           \
    __builtin_amdgcn_sched_barrier(0);                       \
  } while (0)

// Same-wave cross-lane LDS exchange fence: the compiler's per-thread alias
// analysis does NOT order a lane's read of another lane's write. This pins
// instruction order (memory clobber), waits for the writes to land in LDS
// (lgkmcnt), and blocks MIR re-scheduling (sched_barrier).
#define WAVE_LDS_FENCE()                                     \
  do {                                                       \
    asm volatile("s_waitcnt lgkmcnt(0)" ::: "memory");       \
    __builtin_amdgcn_sched_barrier(0);                       \
  } while (0)

__device__ __forceinline__ float bf2f(unsigned short u) {
  unsigned int x = ((unsigned int)u) << 16;
  float f; __builtin_memcpy(&f, &x, 4); return f;
}
__device__ __forceinline__ unsigned short f2hu(float f) {   // f32 -> f16 bits (RNE)
  _Float16 h = (_Float16)f;
  unsigned short u; __builtin_memcpy(&u, &h, 2); return u;
}
__device__ __forceinline__ f16x8 ld8(const _Float16* p) {
  return *(const f16x8*)p;
}

// True iff buffer holds fp32 (low half-words look like huge-exponent bf16s).
__device__ __forceinline__ bool sniff_f32(const unsigned short* p) {
  int cnt = 0;
#pragma unroll 4
  for (int i = 0; i < 128; i += 2) {
    if ((p[i] & 0x7F80) >= 0x4800) cnt++;   // |bf16| >= 2^17: impossible for data
  }
  return cnt >= 4;
}
// weight fetch: fp32 or bf16 source -> f16 bits
__device__ __forceinline__ unsigned short geth(const void* p, size_t i, bool f32) {
  float v = f32 ? ((const float*)p)[i] : bf2f(((const unsigned short*)p)[i]);
  return f2hu(v);
}

// ---------------------------------------------------------------------------
// prep: transposed/concatenated f16 weights + bias.
// Per-layer block (el): Wt[96][256]@0, Ut[96][256]@24576, Wgt[768][96]@49152,
// Gt[768][96]@122880. Block 196608. Bias [2][768] @393216.
// ---------------------------------------------------------------------------
__global__ void prep_kernel(const unsigned short* __restrict__ xprobe,
                            const void* __restrict__ Wd,
                            const void* __restrict__ Wdg,
                            const void* __restrict__ Wo,
                            const void* __restrict__ Wog,
                            const void* __restrict__ Ud,
                            const void* __restrict__ Udg,
                            const void* __restrict__ Uo,
                            const void* __restrict__ Uog,
                            const void* __restrict__ bvec,
                            unsigned short* __restrict__ wbuf) {
  int idx = blockIdx.x * 256 + threadIdx.x;
  if (idx >= 394752) return;
  bool f32 = sniff_f32(xprobe);
  if (idx >= 393216) { wbuf[idx] = geth(bvec, idx - 393216, f32); return; }
  int l = idx / 196608, id = idx % 196608;
  unsigned short v;
  if (id < 24576) {                         // Wt[n][k]
    int n = id >> 8, k = id & 255;
    v = (n < 64) ? geth(Wd, (size_t)l * 16384 + k * 64 + n, f32)
                 : geth(Wo, (size_t)l * 8192 + k * 32 + (n - 64), f32);
  } else if (id < 49152) {                  // Ut[n][k]
    int q = id - 24576; int n = q >> 8, k = q & 255;
    v = (n < 64) ? geth(Ud, (size_t)l * 16384 + k * 64 + n, f32)
                 : geth(Uo, (size_t)l * 8192 + k * 32 + (n - 64), f32);
  } else if (id < 122880) {                 // Wgt[n][k]
    int q = id - 49152; int n = q / 96, k = q % 96;
    v = (k < 64) ? geth(Wdg, (size_t)l * 49152 + k * 768 + n, f32)
                 : geth(Wog, (size_t)l * 24576 + (k - 64) * 768 + n, f32);
  } else {                                  // Gt[n][k]
    int q = id - 122880; int n = q / 96, k = q % 96;
    v = (k < 64) ? geth(Udg, (size_t)l * 49152 + k * 768 + n, f32)
                 : geth(Uog, (size_t)l * 24576 + (k - 64) * 768 + n, f32);
  }
  wbuf[(size_t)l * 196608 + id] = v;
}

// ---------------------------------------------------------------------------
// g12: wxc = (X-chunk @ W) @ Wg + b (fp32 result). 64 chunk-rows/WG.
// xmode: 0 = X bf16, 1 = sniff, 2 = X fp32.
// Chunk row R = b*steps + i  ->  X row b*512 + t0 + i.
// ---------------------------------------------------------------------------
__global__ __launch_bounds__(256) void g12_kernel(
    const void* __restrict__ X,              // [131072,256] bf16 or f32
    int xmode,
    const _Float16* __restrict__ Wt,         // [96,256] f16
    const _Float16* __restrict__ Wgt,        // [768,96] f16
    const _Float16* __restrict__ bv,         // [768] f16
    float* __restrict__ wxc,                 // [256*steps,768] fp32
    int t0, int lsteps) {
  __shared__ __align__(16) _Float16 Pl[64 * 104];
  const int tid = threadIdx.x;
  const int w = tid >> 6, lane = tid & 63;
  const int ml = lane & 15, kg = lane >> 4;
  const int r0 = blockIdx.x * 64;
  const int smask = (1 << lsteps) - 1;
  const f32x4 z4 = {0.f, 0.f, 0.f, 0.f};

  const bool xf32 = (xmode == 2) ||
                    (xmode == 1 && sniff_f32((const unsigned short*)X));

  // GEMM1: P[16,96] = Xrows @ W[256,96]
  f32x4 acc1[6];
  const int R = r0 + w * 16 + ml;
  const int xrow = ((R >> lsteps) << 9) + t0 + (R & smask);
  const size_t abase = (size_t)xrow * 256 + kg * 8;
#pragma unroll
  for (int ks = 0; ks < 8; ks++) {
    f16x8 a;
    if (xf32) {
      const float* p = (const float*)X + abase + ks * 32;
#pragma unroll
      for (int j = 0; j < 8; j++) a[j] = (_Float16)p[j];
    } else {
      const unsigned short* p = (const unsigned short*)X + abase + ks * 32;
#pragma unroll
      for (int j = 0; j < 8; j++) a[j] = (_Float16)bf2f(p[j]);
    }
#pragma unroll
    for (int nt = 0; nt < 6; nt++) {
      f16x8 b = ld8(Wt + (nt * 16 + ml) * 256 + ks * 32 + kg * 8);
      acc1[nt] = MFMA16(a, b, ks ? acc1[nt] : z4);
    }
  }
#pragma unroll
  for (int nt = 0; nt < 6; nt++)
#pragma unroll
    for (int r = 0; r < 4; r++)
      Pl[(w * 16 + kg * 4 + r) * 104 + nt * 16 + ml] = (_Float16)acc1[nt][r];
  __syncthreads();

  // GEMM2: wxc[16,768] = P[16,96] @ Wg[96,768] + b
  f16x8 afr[3];
#pragma unroll
  for (int ks = 0; ks < 3; ks++)
    afr[ks] = ld8(Pl + (w * 16 + ml) * 104 + ks * 32 + kg * 8);
#pragma unroll
  for (int half = 0; half < 2; half++) {
    f32x4 acc[24];
#pragma unroll
    for (int ks = 0; ks < 3; ks++)
#pragma unroll
      for (int nt = 0; nt < 24; nt++) {
        int cb = half * 384 + nt * 16;
        f16x8 b = ld8(Wgt + (size_t)(cb + ml) * 96 + ks * 32 + kg * 8);
        acc[nt] = MFMA16(afr[ks], b, ks ? acc[nt] : z4);
      }
#pragma unroll
    for (int nt = 0; nt < 24; nt++) {
      int cb = half * 384 + nt * 16;
      float bias = (float)bv[cb + ml];
#pragma unroll
      for (int r = 0; r < 4; r++)
        wxc[(size_t)(r0 + w * 16 + kg * 4 + r) * 768 + cb + ml] =
            acc[nt][r] + bias;
    }
  }
}

// ---------------------------------------------------------------------------
// scan: one WG per batch row; `steps` GRU steps; h carried fp32 in hstate.
// M-slot packing: A-row0 = hi, A-row1 = lo residual; result = Drow0 + Drow1
// (exact h / t1 into the fp16 GEMMs; only static weight quant remains).
// GEMM A: t1[96]  = h[256] @ U[256,96]   (A from LDS, U pinned in VGPRs)
// GEMM B: uh[768] = t1[96] @ G[96,768]   (G pinned in VGPRs)
// Two lgkmcnt-only barriers per step (t1-exchange, h-exchange). uh is
// wave-private: wave w owns cols {s*256 + w*64 .. +63} per gate segment s;
// its write->read is cross-lane within the wave -> explicit WAVE_LDS_FENCE
// (per-thread alias analysis would otherwise hoist the reads; R1-R3 bug).
// ---------------------------------------------------------------------------
__global__ __launch_bounds__(256, 1) void scan_kernel(
    const float* __restrict__ wxc,           // [256*steps,768] fp32
    const _Float16* __restrict__ Ut,         // [96,256] f16
    const _Float16* __restrict__ Gt,         // [768,96] f16
    float* __restrict__ xout,                // [B*T,256] fp32 full tensor
    float* __restrict__ hstate,              // [256,256] fp32 carry
    float* __restrict__ hT,                  // pre-offset; stride 512 per b
    int t0, int steps, int first) {
  __shared__ __align__(16) _Float16 hp_lds[512];   // [0:256)=hi, [256:512)=lo
  __shared__ __align__(16) _Float16 t1_lds[192];   // [0:96)=hi, [96:192)=lo
  __shared__ float uh_lds[768];                    // wave-private: [w*192 ..]
  const int tid = threadIdx.x;
  const int b = blockIdx.x;
  const int w = tid >> 6, lane = tid & 63;
  const int ml = lane & 15, kg = lane >> 4;
  const f32x4 z4 = {0.f, 0.f, 0.f, 0.f};

  // GEMM-A N-tile assignment: w0:{0,1} w1:{2,3} w2:{4} w3:{5}
  const int tA = (w < 2) ? 2 * w : (2 + w);
  f16x8 uf[2][8];
#pragma unroll
  for (int i = 0; i < 2; i++) {
    int tile = tA + i; if (tile > 5) tile = 5;
    const _Float16* up = Ut + (size_t)(tile * 16 + ml) * 256 + kg * 8;
#pragma unroll
    for (int ks = 0; ks < 8; ks++) uf[i][ks] = ld8(up + ks * 32);
  }
  // GEMM-B fragments: wave w owns, for each segment s (z/r/c), the 4 tiles
  // covering cols s*256 + w*64 .. +63  (global tile g = s*16 + w*4 + k).
  f16x8 gf[12][3];
#pragma unroll
  for (int nt = 0; nt < 12; nt++) {
    const int g = (nt >> 2) * 16 + w * 4 + (nt & 3);
    const _Float16* gp = Gt + (size_t)(g * 16 + ml) * 96 + kg * 8;
#pragma unroll
    for (int ks = 0; ks < 3; ks++) gf[nt][ks] = ld8(gp + ks * 32);
  }

  float hcur = first ? 0.f : hstate[b * 256 + tid];
  {
    _Float16 hi = (_Float16)hcur;
    hp_lds[tid] = hi;
    hp_lds[256 + tid] = (_Float16)(hcur - (float)hi);
  }
  const float* wrow = wxc + (size_t)b * steps * 768;
  __syncthreads();   // once per kernel: full-strength barrier, cost irrelevant

  // A-row0 (lanes ml even) reads hi, A-row1 (ml odd) reads lo; rows 2-15
  // are don't-care (they read hi/lo again — valid numbers, rows ignored).
  const _Float16* hpf = hp_lds + (ml & 1) * 256 + kg * 8;
  const _Float16* t1f = t1_lds + (ml & 1) * 96 + kg * 8;

  for (int t = 0; t < steps; t++) {
    // Issue previous step's output store + this step's wx loads here: their
    // latency hides behind GEMM A/B (and no barrier ever drains vmcnt).
    if (t > 0) xout[(size_t)(b * 512 + t0 + t - 1) * 256 + tid] = hcur;
    const float* cw = wrow + (size_t)t * 768;
    float wz = cw[tid], wr = cw[256 + tid], wc = cw[512 + tid];

    // ---- GEMM A (two independent K-half chains per tile) ----
    f32x4 aA0[2], aA1[2];
#pragma unroll
    for (int ks = 0; ks < 8; ks++) {
      f16x8 a = ld8(hpf + ks * 32);
      int hh = ks >> 2;
      aA0[hh] = MFMA16(a, uf[0][ks], (ks & 3) ? aA0[hh] : z4);
      if (w < 2) aA1[hh] = MFMA16(a, uf[1][ks], (ks & 3) ? aA1[hh] : z4);
    }
    if (lane < 16) {               // reg0 = hi-row result, reg1 = lo-row result
      float v0 = aA0[0][0] + aA0[0][1] + aA0[1][0] + aA0[1][1];
      _Float16 hi0 = (_Float16)v0;
      t1_lds[tA * 16 + lane] = hi0;
      t1_lds[96 + tA * 16 + lane] = (_Float16)(v0 - (float)hi0);
      if (w < 2) {
        float v1 = aA1[0][0] + aA1[0][1] + aA1[1][0] + aA1[1][1];
        _Float16 hi1 = (_Float16)v1;
        t1_lds[(tA + 1) * 16 + lane] = hi1;
        t1_lds[96 + (tA + 1) * 16 + lane] = (_Float16)(v1 - (float)hi1);
      }
    }
    BAR_LDS();

    // ---- GEMM B ----
    f16x8 tf0 = ld8(t1f), tf1 = ld8(t1f + 32), tf2 = ld8(t1f + 64);
    f32x4 ub[12];
#pragma unroll
    for (int nt = 0; nt < 12; nt++) ub[nt] = MFMA16(tf0, gf[nt][0], z4);
#pragma unroll
    for (int nt = 0; nt < 12; nt++) ub[nt] = MFMA16(tf1, gf[nt][1], ub[nt]);
#pragma unroll
    for (int nt = 0; nt < 12; nt++) ub[nt] = MFMA16(tf2, gf[nt][2], ub[nt]);
    // wave-private uh: col s*256 + w*64 + k*16 + c -> uh_lds[w*192+s*64+k*16+c]
    if (lane < 16) {
#pragma unroll
      for (int nt = 0; nt < 12; nt++)
        uh_lds[w * 192 + (nt >> 2) * 64 + (nt & 3) * 16 + lane] =
            ub[nt][0] + ub[nt][1];
    }
    // Cross-lane same-wave exchange: MUST fence (R1-R3 root cause).
    WAVE_LDS_FENCE();

    // ---- gates (thread tid owns hidden column tid = w*64 + lane) ----
    float uz = uh_lds[w * 192 + lane];
    float ur = uh_lds[w * 192 + 64 + lane];
    float uc = uh_lds[w * 192 + 128 + lane];
    float z = __builtin_amdgcn_rcpf(1.f + __expf(-(wz + uz)));
    float r = __builtin_amdgcn_rcpf(1.f + __expf(-(wr + ur)));
    float cc = 1.f - 2.f * __builtin_amdgcn_rcpf(1.f + __expf(2.f * (wc + r * uc)));
    hcur = z * hcur + (1.f - z) * cc;
    {
      _Float16 hi = (_Float16)hcur;
      hp_lds[tid] = hi;
      hp_lds[256 + tid] = (_Float16)(hcur - (float)hi);
    }
    BAR_LDS();
  }
  xout[(size_t)(b * 512 + t0 + steps - 1) * 256 + tid] = hcur;
  hstate[b * 256 + tid] = hcur;
  hT[(size_t)b * 512 + tid] = hcur;
}

// ---------------------------------------------------------------------------
extern "C" void kernel_launch(void* const* d_in, const int* in_sizes, int n_in,
                              void* d_out, int out_size, void* d_ws, size_t ws_size,
                              hipStream_t stream) {
  (void)in_sizes; (void)n_in; (void)out_size;
  const unsigned short* x = (const unsigned short*)d_in[0];
  float* outF = (float*)d_out;

  // ws layout: wbuf f16 (394752 el = 789504 B) | hstate (256KB) | wxc f32
  unsigned short* wbuf   = (unsigned short*)d_ws;
  float*          hstate = (float*)((char*)d_ws + 790528);
  float*          wxc    = (float*)((char*)d_ws + 1052672);
  const size_t base = 1052672;
  const size_t wx_full = 402653184ull;        // 131072*768*4 bytes

  int nc = 1;
  while (nc < 256 && base + wx_full / nc > ws_size) nc <<= 1;
  const int steps = 512 / nc;
  int lsteps = 0; while ((1 << lsteps) < steps) lsteps++;

  float* xfin = outF;                          // [B,T,256] fp32; doubles as x2
  float* hTb  = outF + (size_t)131072 * 256;   // [B, 2, 256] fp32
  const _Float16* wbh = (const _Float16*)wbuf;
  const _Float16* bbf = wbh + 393216;

  hipLaunchKernelGGL(prep_kernel, dim3(1542), dim3(256), 0, stream,
                     x, d_in[1], d_in[2], d_in[3], d_in[4],
                     d_in[5], d_in[6], d_in[7], d_in[8], d_in[9], wbuf);

  const int g12_grid = (256 * steps) / 64;
  for (int l = 0; l < 2; l++) {
    const _Float16* wl = wbh + (size_t)l * 196608;
    const void* Xl = (l == 0) ? (const void*)x : (const void*)outF;
    const int xmode = (l == 0) ? 1 : 2;
    for (int c = 0; c < nc; c++) {
      hipLaunchKernelGGL(g12_kernel, dim3(g12_grid), dim3(256), 0, stream,
                         Xl, xmode, wl, wl + 49152, bbf + l * 768, wxc,
                         c * steps, lsteps);
      hipLaunchKernelGGL(scan_kernel, dim3(256), dim3(256), 0, stream,
                         wxc, wl + 24576, wl + 122880, xfin, hstate,
                         hTb + l * 256, c * steps, steps, (c == 0) ? 1 : 0);
    }
  }
}